// Round 1
// baseline (1389.561 us; speedup 1.0000x reference)
//
#include <hip/hip_runtime.h>
#include <hip/hip_bf16.h>

#define VOCAB 50000
#define NT    200
#define NTP   256   // padded topics (GEMM1 M)
#define EMB   512
#define BATCH 2048
#define KP    224   // padded K for GEMM2 (topics, 7*32)
#define TK    20

typedef __bf16 bf16x8 __attribute__((ext_vector_type(8)));
typedef float  f32x4  __attribute__((ext_vector_type(4)));

// ---- workspace layout (bytes) ----
#define OFF_EXPWT   0ull                 // [200][50000] f32  = 40,000,000  (row-major, for topk)
#define OFF_EXPWTT  40000000ull          // [50000][224] bf16 = 22,400,000  (transposed, GEMM2 B)
#define OFF_THETAB  62400000ull          // [2048][224] bf16  =    917,504  (theta/rowsum, GEMM2 A)
#define OFF_TOPICA  63317504ull          // [256][512] bf16   =    262,144
#define OFF_ROWSUM  63579648ull          // [200] f32         =        800
#define OFF_STDR    63580448ull          // f32               =          4
#define OFF_TKV     63580464ull          // [200][20] f32
#define OFF_TKI     63596464ull          // [200][20] i32
#define OFF_TKSQ    63612464ull          // [200] f32
// total ~63.62 MB (same as previous version)

// ---------------- theta = softmax(alpha); thetab = theta / rowsum (bf16) ----------------
// NOTE: runs AFTER gemm1 (needs rowsum). Folding 1/rowsum into A makes
// theta @ beta == thetab @ expwtT, eliminating the k_norm pass entirely.
__global__ __launch_bounds__(64) void k_theta(const float* __restrict__ alpha,
                                              const float* __restrict__ rowsum,
                                              float* __restrict__ theta_out,
                                              __bf16* __restrict__ theta_b) {
    int b = blockIdx.x;
    int ln = threadIdx.x;
    const float* row = alpha + (size_t)b * NT;
    float a0 = row[ln], a1 = row[ln + 64], a2 = row[ln + 128];
    float a3 = (ln < 8) ? row[ln + 192] : -1e30f;
    float m = fmaxf(fmaxf(a0, a1), fmaxf(a2, a3));
    #pragma unroll
    for (int off = 32; off; off >>= 1) m = fmaxf(m, __shfl_xor(m, off));
    float e0 = __expf(a0 - m), e1 = __expf(a1 - m), e2 = __expf(a2 - m);
    float e3 = (ln < 8) ? __expf(a3 - m) : 0.f;
    float s = e0 + e1 + e2 + e3;
    #pragma unroll
    for (int off = 32; off; off >>= 1) s += __shfl_xor(s, off);
    float inv = 1.f / s;
    float r0 = 1.f / rowsum[ln];
    float r1 = 1.f / rowsum[ln + 64];
    float r2 = 1.f / rowsum[ln + 128];
    float r3 = (ln < 8) ? 1.f / rowsum[ln + 192] : 0.f;
    float* o = theta_out + (size_t)b * NT;
    __bf16* ob = theta_b + (size_t)b * KP;
    o[ln]       = e0 * inv;  ob[ln]       = (__bf16)(e0 * inv * r0);
    o[ln + 64]  = e1 * inv;  ob[ln + 64]  = (__bf16)(e1 * inv * r1);
    o[ln + 128] = e2 * inv;  ob[ln + 128] = (__bf16)(e2 * inv * r2);
    if (ln < 8)       { o[ln + 192] = e3 * inv; ob[ln + 192] = (__bf16)(e3 * inv * r3); }
    else if (ln < 32) { ob[ln + 192] = (__bf16)0.f; }  // pad cols 200..223
}

// ---------------- topic_emb fp32 -> bf16, pad M to 256 ----------------
__global__ __launch_bounds__(256) void k_topic_cvt(const float* __restrict__ te,
                                                   __bf16* __restrict__ out) {
    int i = blockIdx.x * 256 + threadIdx.x;   // < 256*512
    int t = i >> 9, k = i & 511;
    out[i] = (t < NT) ? (__bf16)te[(size_t)t * EMB + k] : (__bf16)0.f;
}

// ---------------- GEMM1: expwt = exp(topicA @ wemb), rowsum, transposed bf16 out ----------
// block: 256 (padded) topic rows x 64 vocab cols; 4 waves each own 64 rows.
// A fragments come straight from global (topA is 256KB, L2-resident) — no lA staging.
// Epilogue transposes exp() values through LDS and writes expwtT [v][224] coalesced.
__global__ __launch_bounds__(256) void k_gemm1(const float* __restrict__ wemb,
                                               const __bf16* __restrict__ Abf,
                                               float* __restrict__ expwt,
                                               __bf16* __restrict__ expwtT,
                                               float* __restrict__ rowsum) {
    // union: [64][40] bf16 B-tile during K-loop; [64][232] bf16 transpose buf after.
    // pitch 232 bf16 = 464B: 16B-aligned rows, c16-lane write stride 116 dwords
    // -> %32 = 20 -> 8 banks / 16 lanes = 2-way (free per m136).
    __shared__ __align__(16) __bf16 smem[64 * 232];   // 29,696 B
    __bf16* lB = smem;                                 // [64][pitch 40]
    __bf16* tb = smem;                                 // [64][pitch 232]
    int tid = threadIdx.x;
    int v0 = blockIdx.x * 64;
    int w = tid >> 6, ln = tid & 63, quad = ln >> 4, c16 = ln & 15;

    f32x4 acc[4][4];
    #pragma unroll
    for (int mi = 0; mi < 4; ++mi)
        #pragma unroll
        for (int ni = 0; ni < 4; ++ni) acc[mi][ni] = (f32x4){0.f, 0.f, 0.f, 0.f};

    for (int ks = 0; ks < EMB / 32; ++ks) {
        int k0 = ks * 32;
        __syncthreads();
        { // stage B chunk transposed [64 cols][32 k], fp32->bf16 on the fly
            int c = tid & 63, kg = tid >> 6;
            int v = v0 + c;
            bool ok = (v < VOCAB);
            #pragma unroll
            for (int it = 0; it < 8; ++it) {
                int k = kg * 8 + it;
                float val = ok ? wemb[(size_t)(k0 + k) * VOCAB + v] : 0.f;
                lB[c * 40 + k] = (__bf16)val;
            }
        }
        __syncthreads();
        bf16x8 aF[4], bF[4];
        #pragma unroll
        for (int mi = 0; mi < 4; ++mi)
            aF[mi] = *(const bf16x8*)(Abf + (size_t)(w * 64 + mi * 16 + c16) * EMB + k0 + quad * 8);
        #pragma unroll
        for (int ni = 0; ni < 4; ++ni)
            bF[ni] = *(const bf16x8*)(&lB[(ni * 16 + c16) * 40 + quad * 8]);
        #pragma unroll
        for (int mi = 0; mi < 4; ++mi)
            #pragma unroll
            for (int ni = 0; ni < 4; ++ni)
                acc[mi][ni] = __builtin_amdgcn_mfma_f32_16x16x32_bf16(aF[mi], bF[ni], acc[mi][ni], 0, 0, 0);
    }

    __syncthreads();   // all waves done reading lB before tb overwrites it

    // epilogue: exp, f32 row-major store, rowsum, bf16 transpose into LDS
    #pragma unroll
    for (int mi = 0; mi < 4; ++mi) {
        #pragma unroll
        for (int r = 0; r < 4; ++r) {
            int tt = w * 64 + mi * 16 + quad * 4 + r;   // uniform within 16-lane group
            float rs = 0.f;
            #pragma unroll
            for (int ni = 0; ni < 4; ++ni) {
                int vl = ni * 16 + c16;
                int v = v0 + vl;
                if (v < VOCAB) {
                    if (tt < NT) {
                        float e = __expf(acc[mi][ni][r]);
                        expwt[(size_t)tt * VOCAB + v] = e;
                        rs += e;
                        tb[vl * 232 + tt] = (__bf16)e;
                    } else if (tt < KP) {
                        tb[vl * 232 + tt] = (__bf16)0.f;   // pad topics 200..223
                    }
                }
            }
            #pragma unroll
            for (int off = 1; off < 16; off <<= 1) rs += __shfl_xor(rs, off, 16);
            if (tt < NT && c16 == 0) atomicAdd(&rowsum[tt], rs);
        }
    }
    __syncthreads();

    // coalesced writeout: 64 rows x 448B each = 1792 uint4 = 7 per thread
    #pragma unroll
    for (int i = 0; i < 7; ++i) {
        int idx = i * 256 + tid;
        int row = idx / 28, seg = idx % 28;
        if (v0 + row < VOCAB)
            *(uint4*)(expwtT + (size_t)(v0 + row) * KP + seg * 8) =
                *(const uint4*)(&tb[row * 232 + seg * 8]);
    }
}

// ---------------- GEMM2: C = thetab @ expwtT^T, fused Re = -sum log(C)*bow ----------------
// No LDS, no barriers: both operands fragment-load directly from global as 16B bf16x8.
// A (thetab, 0.9MB) and B (expwtT, 22.4MB) are cache-resident; manual 2-deep pipeline.
__global__ __launch_bounds__(256) void k_gemm2(const __bf16* __restrict__ thetab,
                                               const __bf16* __restrict__ expwtT,
                                               const float* __restrict__ bow,
                                               float* __restrict__ Re) {
    int tid = threadIdx.x;
    int m0 = blockIdx.x * 128;
    int v0 = blockIdx.y * 128;
    int w = tid >> 6, ln = tid & 63, quad = ln >> 4, c16 = ln & 15;

    // per-lane row pointers (K-step folds into the load's immediate offset)
    const __bf16* aRow[2];
    #pragma unroll
    for (int mi = 0; mi < 2; ++mi)
        aRow[mi] = thetab + (size_t)(m0 + w * 32 + mi * 16 + c16) * KP + quad * 8;
    const __bf16* bRow[8];
    bool vok[8];
    #pragma unroll
    for (int ni = 0; ni < 8; ++ni) {
        int v = v0 + ni * 16 + c16;
        vok[ni] = (v < VOCAB);
        bRow[ni] = expwtT + (size_t)v * KP + quad * 8;
    }

    bf16x8 bz;
    #pragma unroll
    for (int j = 0; j < 8; ++j) bz[j] = (__bf16)0.f;

    f32x4 acc[2][8];
    #pragma unroll
    for (int mi = 0; mi < 2; ++mi)
        #pragma unroll
        for (int ni = 0; ni < 8; ++ni) acc[mi][ni] = (f32x4){0.f, 0.f, 0.f, 0.f};

    bf16x8 aF[2][2], bF[2][8];
#define LOADK(KS, BUF)                                                          \
    {                                                                           \
        _Pragma("unroll") for (int mi = 0; mi < 2; ++mi)                        \
            aF[BUF][mi] = *(const bf16x8*)(aRow[mi] + (KS) * 32);               \
        _Pragma("unroll") for (int ni = 0; ni < 8; ++ni)                        \
            bF[BUF][ni] = vok[ni] ? *(const bf16x8*)(bRow[ni] + (KS) * 32) : bz;\
    }

    LOADK(0, 0);
    #pragma unroll
    for (int ks = 0; ks < KP / 32; ++ks) {
        int cur = ks & 1;
        if (ks < KP / 32 - 1) LOADK(ks + 1, (ks + 1) & 1);
        #pragma unroll
        for (int mi = 0; mi < 2; ++mi)
            #pragma unroll
            for (int ni = 0; ni < 8; ++ni)
                acc[mi][ni] = __builtin_amdgcn_mfma_f32_16x16x32_bf16(aF[cur][mi], bF[cur][ni],
                                                                      acc[mi][ni], 0, 0, 0);
    }
#undef LOADK

    // fused epilogue: per-row partial of log(C)*bow, reduce over 16 cols, atomic
    #pragma unroll
    for (int mi = 0; mi < 2; ++mi) {
        #pragma unroll
        for (int r = 0; r < 4; ++r) {
            int b = m0 + w * 32 + mi * 16 + quad * 4 + r;
            float s = 0.f;
            #pragma unroll
            for (int ni = 0; ni < 8; ++ni) {
                int v = v0 + ni * 16 + c16;
                if (v < VOCAB)
                    s += __logf(acc[mi][ni][r]) * bow[(size_t)b * VOCAB + v];
            }
            #pragma unroll
            for (int off = 1; off < 16; off <<= 1) s += __shfl_xor(s, off, 16);
            if (c16 == 0) atomicAdd(&Re[b], -s);
        }
    }
}

// ---------------- per-topic top-20 of expwt (order == order of beta) ----------------
__global__ __launch_bounds__(256) void k_topk(const float* __restrict__ expwt,
                                              float* __restrict__ tkv,
                                              int* __restrict__ tki,
                                              float* __restrict__ tksq) {
    __shared__ float lv[256 * TK];
    __shared__ int   li[256 * TK];
    __shared__ int   head[256];
    __shared__ float redv[256];
    __shared__ int   redi[256];
    __shared__ float selv[TK];
    __shared__ int   seli[TK];
    int t = blockIdx.x, tid = threadIdx.x;
    const float* row = expwt + (size_t)t * VOCAB;

    float tv[TK]; int ti[TK];
    #pragma unroll
    for (int i = 0; i < TK; ++i) { tv[i] = -1e30f; ti[i] = 0; }

    for (int v = tid; v < VOCAB; v += 256) {
        float val = row[v];
        if (val > tv[TK - 1]) {
            #pragma unroll
            for (int i = TK - 1; i >= 1; --i) {
                bool sh  = val > tv[i - 1];
                bool put = val > tv[i];
                float nv = sh ? tv[i - 1] : (put ? val : tv[i]);
                int  nix = sh ? ti[i - 1] : (put ? v   : ti[i]);
                tv[i] = nv; ti[i] = nix;
            }
            if (val > tv[0]) { tv[0] = val; ti[0] = v; }
        }
    }
    #pragma unroll
    for (int i = 0; i < TK; ++i) { lv[tid * TK + i] = tv[i]; li[tid * TK + i] = ti[i]; }
    head[tid] = 0;
    __syncthreads();

    for (int sel = 0; sel < TK; ++sel) {
        int h = head[tid];
        redv[tid] = (h < TK) ? lv[tid * TK + h] : -1e30f;
        redi[tid] = tid;
        __syncthreads();
        for (int s2 = 128; s2 > 0; s2 >>= 1) {
            if (tid < s2) {
                if (redv[tid + s2] > redv[tid]) {
                    redv[tid] = redv[tid + s2]; redi[tid] = redi[tid + s2];
                }
            }
            __syncthreads();
        }
        if (tid == 0) {
            int wt = redi[0];
            int hh = head[wt];
            selv[sel] = lv[wt * TK + hh];
            seli[sel] = li[wt * TK + hh];
            head[wt] = hh + 1;
        }
        __syncthreads();
    }

    if (tid == 0) {
        float sum = 0.f;
        #pragma unroll
        for (int i = 0; i < TK; ++i) sum += selv[i];
        float inv = 1.f / sum, sq = 0.f;
        #pragma unroll
        for (int i = 0; i < TK; ++i) {
            float nv = selv[i] * inv;
            tkv[t * TK + i] = nv;
            tki[t * TK + i] = seli[i];
            sq += nv * nv;
        }
        tksq[t] = sq;
    }
}

// ---------------- STDR pairs: sum 0.5*||b_i - b_j||^2 over sparse rows ----------------
__global__ __launch_bounds__(256) void k_pairs(const float* __restrict__ tkv,
                                               const int* __restrict__ tki,
                                               const float* __restrict__ tksq,
                                               float* __restrict__ stdr) {
    int p = blockIdx.x * 256 + threadIdx.x;
    float contrib = 0.f;
    if (p < NT * NT) {
        int i = p / NT, j = p % NT;
        float vi[TK], vj[TK]; int ii[TK], ij[TK];
        #pragma unroll
        for (int a = 0; a < TK; ++a) { vi[a] = tkv[i * TK + a]; ii[a] = tki[i * TK + a]; }
        #pragma unroll
        for (int a = 0; a < TK; ++a) { vj[a] = tkv[j * TK + a]; ij[a] = tki[j * TK + a]; }
        float g = 0.f;
        for (int a = 0; a < TK; ++a) {
            #pragma unroll
            for (int b = 0; b < TK; ++b)
                if (ii[a] == ij[b]) g += vi[a] * vj[b];
        }
        float d2 = fmaxf(tksq[i] + tksq[j] - 2.f * g, 0.f);
        contrib = 0.5f * d2;
    }
    __shared__ float red[256];
    red[threadIdx.x] = contrib;
    __syncthreads();
    for (int s = 128; s; s >>= 1) {
        if (threadIdx.x < s) red[threadIdx.x] += red[threadIdx.x + s];
        __syncthreads();
    }
    if (threadIdx.x == 0) atomicAdd(stdr, red[0]);
}

__global__ void k_final(const float* __restrict__ stdr, float* __restrict__ out) {
    out[0] = stdr[0] * (1.f / (float)(NT * NT));
}

extern "C" void kernel_launch(void* const* d_in, const int* in_sizes, int n_in,
                              void* d_out, int out_size, void* d_ws, size_t ws_size,
                              hipStream_t stream) {
    const float* alpha = (const float*)d_in[0];
    const float* bow   = (const float*)d_in[1];
    const float* temb  = (const float*)d_in[2];
    const float* wemb  = (const float*)d_in[3];
    float* out = (float*)d_out;
    char* ws = (char*)d_ws;

    float*  expwt  = (float*)(ws + OFF_EXPWT);
    __bf16* expwtT = (__bf16*)(ws + OFF_EXPWTT);
    __bf16* thetab = (__bf16*)(ws + OFF_THETAB);
    __bf16* topA   = (__bf16*)(ws + OFF_TOPICA);
    float*  rowsum = (float*)(ws + OFF_ROWSUM);
    float*  stdr   = (float*)(ws + OFF_STDR);
    float*  tkv    = (float*)(ws + OFF_TKV);
    int*    tki    = (int*)(ws + OFF_TKI);
    float*  tksq   = (float*)(ws + OFF_TKSQ);

    float* Re        = out;              // [2048]
    float* stdr_out  = out + BATCH;      // [1]
    float* theta_out = out + BATCH + 1;  // [2048*200]

    hipMemsetAsync(Re, 0, BATCH * sizeof(float), stream);
    hipMemsetAsync(ws + OFF_ROWSUM, 0, 804, stream);   // rowsum + stdr accumulator

    k_topic_cvt<<<512, 256, 0, stream>>>(temb, topA);
    k_gemm1<<<(VOCAB + 63) / 64, 256, 0, stream>>>(wemb, topA, expwt, expwtT, rowsum);
    k_theta<<<BATCH, 64, 0, stream>>>(alpha, rowsum, theta_out, thetab);
    k_gemm2<<<dim3(BATCH / 128, (VOCAB + 127) / 128), 256, 0, stream>>>(thetab, expwtT, bow, Re);
    k_topk<<<NT, 256, 0, stream>>>(expwt, tkv, tki, tksq);
    k_pairs<<<(NT * NT + 255) / 256, 256, 0, stream>>>(tkv, tki, tksq, stdr);
    k_final<<<1, 1, 0, stream>>>(stdr, stdr_out);
}

// Round 2
// 1220.564 us; speedup vs baseline: 1.1385x; 1.1385x over previous
//
#include <hip/hip_runtime.h>
#include <hip/hip_bf16.h>

#define VOCAB 50000
#define NT    200
#define NTP   256   // padded topics (GEMM1 M)
#define EMB   512
#define BATCH 2048
#define KP    224   // padded K for GEMM2 (topics, 7*32)
#define TK    20

typedef __bf16 bf16x8 __attribute__((ext_vector_type(8)));
typedef float  f32x4  __attribute__((ext_vector_type(4)));

// ---- workspace layout (bytes) ----
#define OFF_EXPWT   0ull                 // [200][50000] f32  = 40,000,000  (row-major, for topk)
#define OFF_EXPWTT  40000000ull          // [50000][224] bf16 = 22,400,000  (transposed, GEMM2 B)
#define OFF_THETAB  62400000ull          // [2048][224] bf16  =    917,504  (theta/rowsum, GEMM2 A)
#define OFF_TOPICA  63317504ull          // [256][512] bf16   =    262,144
#define OFF_ROWSUM  63579648ull          // [200] f32         =        800
#define OFF_STDR    63580448ull          // f32               =          4
#define OFF_TKV     63580464ull          // [200][20] f32
#define OFF_TKI     63596464ull          // [200][20] i32
#define OFF_TKSQ    63612464ull          // [200] f32
// total ~63.62 MB

// async global->LDS, 16B per lane; LDS dest is wave-uniform base + lane*16
__device__ __forceinline__ void gll16(const void* g, void* l) {
    __builtin_amdgcn_global_load_lds(
        (const __attribute__((address_space(1))) unsigned int*)g,
        (__attribute__((address_space(3))) unsigned int*)l, 16, 0, 0);
}

// swizzled fragment read: logical (row r, 16B-unit q) lives at phys unit q ^ ((r>>1)&3)
#define FRAG(arr, r, q) (*(const bf16x8*)(&(arr)[(((r) * 4 + ((q) ^ (((r) >> 1) & 3))) * 8)]))

// ---------------- theta = softmax(alpha); thetab = theta / rowsum (bf16) ----------------
__global__ __launch_bounds__(64) void k_theta(const float* __restrict__ alpha,
                                              const float* __restrict__ rowsum,
                                              float* __restrict__ theta_out,
                                              __bf16* __restrict__ theta_b) {
    int b = blockIdx.x;
    int ln = threadIdx.x;
    const float* row = alpha + (size_t)b * NT;
    float a0 = row[ln], a1 = row[ln + 64], a2 = row[ln + 128];
    float a3 = (ln < 8) ? row[ln + 192] : -1e30f;
    float m = fmaxf(fmaxf(a0, a1), fmaxf(a2, a3));
    #pragma unroll
    for (int off = 32; off; off >>= 1) m = fmaxf(m, __shfl_xor(m, off));
    float e0 = __expf(a0 - m), e1 = __expf(a1 - m), e2 = __expf(a2 - m);
    float e3 = (ln < 8) ? __expf(a3 - m) : 0.f;
    float s = e0 + e1 + e2 + e3;
    #pragma unroll
    for (int off = 32; off; off >>= 1) s += __shfl_xor(s, off);
    float inv = 1.f / s;
    float r0 = 1.f / rowsum[ln];
    float r1 = 1.f / rowsum[ln + 64];
    float r2 = 1.f / rowsum[ln + 128];
    float r3 = (ln < 8) ? 1.f / rowsum[ln + 192] : 0.f;
    float* o = theta_out + (size_t)b * NT;
    __bf16* ob = theta_b + (size_t)b * KP;
    o[ln]       = e0 * inv;  ob[ln]       = (__bf16)(e0 * inv * r0);
    o[ln + 64]  = e1 * inv;  ob[ln + 64]  = (__bf16)(e1 * inv * r1);
    o[ln + 128] = e2 * inv;  ob[ln + 128] = (__bf16)(e2 * inv * r2);
    if (ln < 8)       { o[ln + 192] = e3 * inv; ob[ln + 192] = (__bf16)(e3 * inv * r3); }
    else if (ln < 32) { ob[ln + 192] = (__bf16)0.f; }  // pad cols 200..223
}

// ---------------- topic_emb fp32 -> bf16, pad M to 256 ----------------
__global__ __launch_bounds__(256) void k_topic_cvt(const float* __restrict__ te,
                                                   __bf16* __restrict__ out) {
    int i = blockIdx.x * 256 + threadIdx.x;   // < 256*512
    int t = i >> 9, k = i & 511;
    out[i] = (t < NT) ? (__bf16)te[(size_t)t * EMB + k] : (__bf16)0.f;
}

// ---------------- GEMM1: expwt = exp(topicA @ wemb), rowsum, transposed bf16 out ----------
__global__ __launch_bounds__(256) void k_gemm1(const float* __restrict__ wemb,
                                               const __bf16* __restrict__ Abf,
                                               float* __restrict__ expwt,
                                               __bf16* __restrict__ expwtT,
                                               float* __restrict__ rowsum) {
    __shared__ __align__(16) __bf16 smem[64 * 232];   // 29,696 B
    __bf16* lB = smem;                                 // [64][pitch 40]
    __bf16* tb = smem;                                 // [64][pitch 232]
    int tid = threadIdx.x;
    int v0 = blockIdx.x * 64;
    int w = tid >> 6, ln = tid & 63, quad = ln >> 4, c16 = ln & 15;

    f32x4 acc[4][4];
    #pragma unroll
    for (int mi = 0; mi < 4; ++mi)
        #pragma unroll
        for (int ni = 0; ni < 4; ++ni) acc[mi][ni] = (f32x4){0.f, 0.f, 0.f, 0.f};

    for (int ks = 0; ks < EMB / 32; ++ks) {
        int k0 = ks * 32;
        __syncthreads();
        { // stage B chunk transposed [64 cols][32 k], fp32->bf16 on the fly
            int c = tid & 63, kg = tid >> 6;
            int v = v0 + c;
            bool ok = (v < VOCAB);
            #pragma unroll
            for (int it = 0; it < 8; ++it) {
                int k = kg * 8 + it;
                float val = ok ? wemb[(size_t)(k0 + k) * VOCAB + v] : 0.f;
                lB[c * 40 + k] = (__bf16)val;
            }
        }
        __syncthreads();
        bf16x8 aF[4], bF[4];
        #pragma unroll
        for (int mi = 0; mi < 4; ++mi)
            aF[mi] = *(const bf16x8*)(Abf + (size_t)(w * 64 + mi * 16 + c16) * EMB + k0 + quad * 8);
        #pragma unroll
        for (int ni = 0; ni < 4; ++ni)
            bF[ni] = *(const bf16x8*)(&lB[(ni * 16 + c16) * 40 + quad * 8]);
        #pragma unroll
        for (int mi = 0; mi < 4; ++mi)
            #pragma unroll
            for (int ni = 0; ni < 4; ++ni)
                acc[mi][ni] = __builtin_amdgcn_mfma_f32_16x16x32_bf16(aF[mi], bF[ni], acc[mi][ni], 0, 0, 0);
    }

    __syncthreads();   // all waves done reading lB before tb overwrites it

    // epilogue: exp, f32 row-major store, rowsum, bf16 transpose into LDS
    #pragma unroll
    for (int mi = 0; mi < 4; ++mi) {
        #pragma unroll
        for (int r = 0; r < 4; ++r) {
            int tt = w * 64 + mi * 16 + quad * 4 + r;   // uniform within 16-lane group
            float rs = 0.f;
            #pragma unroll
            for (int ni = 0; ni < 4; ++ni) {
                int vl = ni * 16 + c16;
                int v = v0 + vl;
                if (v < VOCAB) {
                    if (tt < NT) {
                        float e = __expf(acc[mi][ni][r]);
                        expwt[(size_t)tt * VOCAB + v] = e;
                        rs += e;
                        tb[vl * 232 + tt] = (__bf16)e;
                    } else if (tt < KP) {
                        tb[vl * 232 + tt] = (__bf16)0.f;   // pad topics 200..223
                    }
                }
            }
            #pragma unroll
            for (int off = 1; off < 16; off <<= 1) rs += __shfl_xor(rs, off, 16);
            if (tt < NT && c16 == 0) atomicAdd(&rowsum[tt], rs);
        }
    }
    __syncthreads();

    // coalesced writeout: 64 rows x 448B each = 1792 uint4 = 7 per thread
    #pragma unroll
    for (int i = 0; i < 7; ++i) {
        int idx = i * 256 + tid;
        int row = idx / 28, seg = idx % 28;
        if (v0 + row < VOCAB)
            *(uint4*)(expwtT + (size_t)(v0 + row) * KP + seg * 8) =
                *(const uint4*)(&tb[row * 232 + seg * 8]);
    }
}

// ---------------- GEMM2: C = thetab @ expwtT^T, fused Re = -sum log(C)*bow ----------------
// m97-structure: LDS double-buffer, global_load_lds(16B) staging shared by the block's
// 4 waves, both-sides XOR swizzle for conflict-free ds_read_b128 fragments.
__global__ __launch_bounds__(256, 3) void k_gemm2(const __bf16* __restrict__ thetab,
                                                  const __bf16* __restrict__ expwtT,
                                                  const float* __restrict__ bow,
                                                  float* __restrict__ Re) {
    __shared__ __align__(16) __bf16 sA[2][128 * 32];   // 8KB x2
    __shared__ __align__(16) __bf16 sB[2][128 * 32];   // 8KB x2
    int tid = threadIdx.x;

    // XCD-chunked bijective swizzle: nwg = 16*391 = 6256 = 8*782
    int flat = blockIdx.x + blockIdx.y * 16;
    int swz  = (flat & 7) * 782 + (flat >> 3);
    int m0 = (swz & 15) * 128;          // batch tile
    int v0 = (swz >> 4) * 128;          // vocab tile

    int wv = tid >> 6, ln = tid & 63, quad = ln >> 4, c16 = ln & 15;

    f32x4 acc[2][8];
    #pragma unroll
    for (int mi = 0; mi < 2; ++mi)
        #pragma unroll
        for (int ni = 0; ni < 8; ++ni) acc[mi][ni] = (f32x4){0.f, 0.f, 0.f, 0.f};

    // stage one 128x32 bf16 tile of A and B: 512 slots of 16B each, 2 slots/thread.
    // linear LDS dest (slot s -> bytes s*16); source pre-swizzled so that logical
    // 16B-unit u of row r sits at phys unit u ^ ((r>>1)&3)  (rule #21).
#define STAGE2(buf, ks)                                                         \
    {                                                                           \
        int k0_ = (ks) * 32;                                                    \
        _Pragma("unroll") for (int j = 0; j < 2; ++j) {                         \
            int s   = j * 256 + wv * 64 + ln;                                   \
            int row = s >> 2;                                                   \
            int ul  = (s & 3) ^ ((s >> 3) & 3);                                 \
            gll16(thetab + (size_t)(m0 + row) * KP + k0_ + ul * 8,              \
                  &sA[buf][(j * 256 + wv * 64) * 8]);                           \
            int vr = v0 + row; vr = (vr < VOCAB) ? vr : (VOCAB - 1);            \
            gll16(expwtT + (size_t)vr * KP + k0_ + ul * 8,                      \
                  &sB[buf][(j * 256 + wv * 64) * 8]);                           \
        }                                                                       \
    }

    STAGE2(0, 0);
    __syncthreads();   // drains vmcnt(0): tile 0 resident

    for (int ks = 0; ks < KP / 32; ++ks) {
        int cur = ks & 1;
        if (ks < KP / 32 - 1) STAGE2(cur ^ 1, ks + 1);   // prefetch next tile
        bf16x8 aF[2], bF[8];
        #pragma unroll
        for (int mi = 0; mi < 2; ++mi)
            aF[mi] = FRAG(sA[cur], wv * 32 + mi * 16 + c16, quad);
        #pragma unroll
        for (int ni = 0; ni < 8; ++ni)
            bF[ni] = FRAG(sB[cur], ni * 16 + c16, quad);
        #pragma unroll
        for (int mi = 0; mi < 2; ++mi)
            #pragma unroll
            for (int ni = 0; ni < 8; ++ni)
                acc[mi][ni] = __builtin_amdgcn_mfma_f32_16x16x32_bf16(aF[mi], bF[ni],
                                                                      acc[mi][ni], 0, 0, 0);
        __syncthreads();   // next tile staged + all waves done with cur
    }
#undef STAGE2

    // fused epilogue: per-row partial of log(C)*bow, reduce over 16 cols, atomic
    #pragma unroll
    for (int mi = 0; mi < 2; ++mi) {
        #pragma unroll
        for (int r = 0; r < 4; ++r) {
            int b = m0 + wv * 32 + mi * 16 + quad * 4 + r;
            float s = 0.f;
            #pragma unroll
            for (int ni = 0; ni < 8; ++ni) {
                int v = v0 + ni * 16 + c16;
                if (v < VOCAB)
                    s += __logf(acc[mi][ni][r]) * bow[(size_t)b * VOCAB + v];
            }
            #pragma unroll
            for (int off = 1; off < 16; off <<= 1) s += __shfl_xor(s, off, 16);
            if (c16 == 0) atomicAdd(&Re[b], -s);
        }
    }
}

// ---------------- per-topic top-20 of expwt (order == order of beta) ----------------
__global__ __launch_bounds__(256) void k_topk(const float* __restrict__ expwt,
                                              float* __restrict__ tkv,
                                              int* __restrict__ tki,
                                              float* __restrict__ tksq) {
    __shared__ float lv[256 * TK];
    __shared__ int   li[256 * TK];
    __shared__ int   head[256];
    __shared__ float redv[256];
    __shared__ int   redi[256];
    __shared__ float selv[TK];
    __shared__ int   seli[TK];
    int t = blockIdx.x, tid = threadIdx.x;
    const float* row = expwt + (size_t)t * VOCAB;

    float tv[TK]; int ti[TK];
    #pragma unroll
    for (int i = 0; i < TK; ++i) { tv[i] = -1e30f; ti[i] = 0; }

    for (int v = tid; v < VOCAB; v += 256) {
        float val = row[v];
        if (val > tv[TK - 1]) {
            #pragma unroll
            for (int i = TK - 1; i >= 1; --i) {
                bool sh  = val > tv[i - 1];
                bool put = val > tv[i];
                float nv = sh ? tv[i - 1] : (put ? val : tv[i]);
                int  nix = sh ? ti[i - 1] : (put ? v   : ti[i]);
                tv[i] = nv; ti[i] = nix;
            }
            if (val > tv[0]) { tv[0] = val; ti[0] = v; }
        }
    }
    #pragma unroll
    for (int i = 0; i < TK; ++i) { lv[tid * TK + i] = tv[i]; li[tid * TK + i] = ti[i]; }
    head[tid] = 0;
    __syncthreads();

    for (int sel = 0; sel < TK; ++sel) {
        int h = head[tid];
        redv[tid] = (h < TK) ? lv[tid * TK + h] : -1e30f;
        redi[tid] = tid;
        __syncthreads();
        for (int s2 = 128; s2 > 0; s2 >>= 1) {
            if (tid < s2) {
                if (redv[tid + s2] > redv[tid]) {
                    redv[tid] = redv[tid + s2]; redi[tid] = redi[tid + s2];
                }
            }
            __syncthreads();
        }
        if (tid == 0) {
            int wt = redi[0];
            int hh = head[wt];
            selv[sel] = lv[wt * TK + hh];
            seli[sel] = li[wt * TK + hh];
            head[wt] = hh + 1;
        }
        __syncthreads();
    }

    if (tid == 0) {
        float sum = 0.f;
        #pragma unroll
        for (int i = 0; i < TK; ++i) sum += selv[i];
        float inv = 1.f / sum, sq = 0.f;
        #pragma unroll
        for (int i = 0; i < TK; ++i) {
            float nv = selv[i] * inv;
            tkv[t * TK + i] = nv;
            tki[t * TK + i] = seli[i];
            sq += nv * nv;
        }
        tksq[t] = sq;
    }
}

// ---------------- STDR pairs: sum 0.5*||b_i - b_j||^2 over sparse rows ----------------
__global__ __launch_bounds__(256) void k_pairs(const float* __restrict__ tkv,
                                               const int* __restrict__ tki,
                                               const float* __restrict__ tksq,
                                               float* __restrict__ stdr) {
    int p = blockIdx.x * 256 + threadIdx.x;
    float contrib = 0.f;
    if (p < NT * NT) {
        int i = p / NT, j = p % NT;
        float vi[TK], vj[TK]; int ii[TK], ij[TK];
        #pragma unroll
        for (int a = 0; a < TK; ++a) { vi[a] = tkv[i * TK + a]; ii[a] = tki[i * TK + a]; }
        #pragma unroll
        for (int a = 0; a < TK; ++a) { vj[a] = tkv[j * TK + a]; ij[a] = tki[j * TK + a]; }
        float g = 0.f;
        for (int a = 0; a < TK; ++a) {
            #pragma unroll
            for (int b = 0; b < TK; ++b)
                if (ii[a] == ij[b]) g += vi[a] * vj[b];
        }
        float d2 = fmaxf(tksq[i] + tksq[j] - 2.f * g, 0.f);
        contrib = 0.5f * d2;
    }
    __shared__ float red[256];
    red[threadIdx.x] = contrib;
    __syncthreads();
    for (int s = 128; s; s >>= 1) {
        if (threadIdx.x < s) red[threadIdx.x] += red[threadIdx.x + s];
        __syncthreads();
    }
    if (threadIdx.x == 0) atomicAdd(stdr, red[0]);
}

__global__ void k_final(const float* __restrict__ stdr, float* __restrict__ out) {
    out[0] = stdr[0] * (1.f / (float)(NT * NT));
}

extern "C" void kernel_launch(void* const* d_in, const int* in_sizes, int n_in,
                              void* d_out, int out_size, void* d_ws, size_t ws_size,
                              hipStream_t stream) {
    const float* alpha = (const float*)d_in[0];
    const float* bow   = (const float*)d_in[1];
    const float* temb  = (const float*)d_in[2];
    const float* wemb  = (const float*)d_in[3];
    float* out = (float*)d_out;
    char* ws = (char*)d_ws;

    float*  expwt  = (float*)(ws + OFF_EXPWT);
    __bf16* expwtT = (__bf16*)(ws + OFF_EXPWTT);
    __bf16* thetab = (__bf16*)(ws + OFF_THETAB);
    __bf16* topA   = (__bf16*)(ws + OFF_TOPICA);
    float*  rowsum = (float*)(ws + OFF_ROWSUM);
    float*  stdr   = (float*)(ws + OFF_STDR);
    float*  tkv    = (float*)(ws + OFF_TKV);
    int*    tki    = (int*)(ws + OFF_TKI);
    float*  tksq   = (float*)(ws + OFF_TKSQ);

    float* Re        = out;              // [2048]
    float* stdr_out  = out + BATCH;      // [1]
    float* theta_out = out + BATCH + 1;  // [2048*200]

    hipMemsetAsync(Re, 0, BATCH * sizeof(float), stream);
    hipMemsetAsync(ws + OFF_ROWSUM, 0, 804, stream);   // rowsum + stdr accumulator

    k_topic_cvt<<<512, 256, 0, stream>>>(temb, topA);
    k_gemm1<<<(VOCAB + 63) / 64, 256, 0, stream>>>(wemb, topA, expwt, expwtT, rowsum);
    k_theta<<<BATCH, 64, 0, stream>>>(alpha, rowsum, theta_out, thetab);
    k_gemm2<<<dim3(BATCH / 128, (VOCAB + 127) / 128), 256, 0, stream>>>(thetab, expwtT, bow, Re);
    k_topk<<<NT, 256, 0, stream>>>(expwt, tkv, tki, tksq);
    k_pairs<<<(NT * NT + 255) / 256, 256, 0, stream>>>(tkv, tki, tksq, stdr);
    k_final<<<1, 1, 0, stream>>>(stdr, stdr_out);
}